// Round 13
// baseline (28.052 us; speedup 1.0000x reference)
//
#include <hip/hip_runtime.h>
#include <hip/hip_bf16.h>
#include <cmath>

// Problem constants
#define BB 128
#define MM 64
#define DD 64
#define PP 1024
#define AN 21
#define UVP 68                          // padded u/v LDS row stride

typedef __attribute__((ext_vector_type(8))) short bf16x8;   // 8 bf16 = 4 VGPRs
typedef __attribute__((ext_vector_type(4))) float f32x4;    // MFMA C/D + pk math
typedef __attribute__((ext_vector_type(2))) float f32x2;    // v_pk_*_f32 pairs

// paired tanh-approx GELU: 6 packed-f32 VALU + 4 trans per TWO gelus.
__device__ __forceinline__ f32x2 gelu2(f32x2 x) {
    const f32x2 x2 = x * x;                                        // pk_mul
    const f32x2 q  = __builtin_elementwise_fma(
        x2, (f32x2){0.044715f, 0.044715f}, (f32x2){1.0f, 1.0f});   // pk_fma
    const f32x2 p  = x * q;                                        // pk_mul
    const f32x2 zm = p * (f32x2){2.3022150322f, 2.3022150322f};    // pk_mul
    f32x2 z;
    z[0] = __builtin_amdgcn_exp2f(zm[0]);                          // trans
    z[1] = __builtin_amdgcn_exp2f(zm[1]);                          // trans
    const f32x2 zp = z + (f32x2){1.0f, 1.0f};                      // pk_add
    f32x2 r;
    r[0] = __builtin_amdgcn_rcpf(zp[0]);                           // trans
    r[1] = __builtin_amdgcn_rcpf(zp[1]);                           // trans
    return __builtin_elementwise_fma(-x, r, x);                    // pk_fma
}

// pack 2 floats -> 1 u32 of 2 bf16 (emits v_cvt_pk_bf16_f32)
__device__ __forceinline__ unsigned pk2bf(float lo, float hi) {
    __hip_bfloat162 t = __float22bfloat162_rn(make_float2(lo, hi));
    unsigned u; __builtin_memcpy(&u, &t, 4);
    return u;
}

// butterfly sum over each 16-lane row via DPP (xor 1,2,4,8)
__device__ __forceinline__ float row_sum16(float x) {
    int t;
    t = __builtin_amdgcn_update_dpp(0, __float_as_int(x), 0xB1, 0xF, 0xF, true); // xor1
    x += __int_as_float(t);
    t = __builtin_amdgcn_update_dpp(0, __float_as_int(x), 0x4E, 0xF, 0xF, true); // xor2
    x += __int_as_float(t);
    t = __builtin_amdgcn_update_dpp(0, __float_as_int(x), 0x141, 0xF, 0xF, true); // xor4
    x += __int_as_float(t);
    t = __builtin_amdgcn_update_dpp(0, __float_as_int(x), 0x140, 0xF, 0xF, true); // xor8
    x += __int_as_float(t);
    return x;
}

// ---------------------------------------------------------------------------
// FUSED kernel, diagonal-packed, 512-thread WGs (8 waves, 2 column-slots
// each: ss = tt*8 + wave). Round-12 analysis: body was ~60% stall at 4
// waves/SIMD (grid-limited); doubling waves per WG raises residency to the
// VGPR cap (6/SIMD at 76 VGPR) WITHOUT duplicating the prologue (same 1024
// WGs). Work, arithmetic, and stores are bit-identical to round 12.
// blk 0..5: strictly-upper 16x16 blocks (ib<jb).
// blk 6..7: two diagonal triangles packed per WG via column-slot scheme
//   (slot s: lanes r<s -> pair (r,s) of d0; r>=s -> (r-s,16-s) of d1;
//    slot 0 duplicates slot 8 -- identical-value store race, benign).
// Prologue: u/v tiles MFMA'd into LDS (waves 0..3 packed / 0..1 off-diag);
// W1/W2 fragments from stride-64 scalar loads (L1-hot).
// ---------------------------------------------------------------------------
__global__ __launch_bounds__(512) void k_fused(
    const int* __restrict__ positions, const int* __restrict__ amino,
    const float* __restrict__ pos_table, const float* __restrict__ aa_table,
    const float* __restrict__ W1, const float* __restrict__ b1,
    const float* __restrict__ W2, const float* __restrict__ b2,
    const float* __restrict__ W3, const float* __restrict__ b3,
    float* __restrict__ out)
{
    __shared__ __align__(16) float tiles[4][16][UVP];
    const int lane = threadIdx.x & 63;
    const int wave = threadIdx.x >> 6;   // 0..7
    const int r = lane & 15;        // A row (build) / C col (output feature)
    const int g = lane >> 4;        // k-group

    const int blk = blockIdx.x;     // 0..7
    const int b   = blockIdx.y;     // 0..127
    const bool packed = (blk >= 6);
    // off-diag (ib, jb) tables, 3 bits each: blocks {01,02,03,12,13,23}
    const int ib = (0x11200u >> (3 * blk)) & 7;
    const int jb = (0x1B4D1u >> (3 * blk)) & 7;
    const int dlo = packed ? 2 * (blk - 6) : 0;     // packed triangle tiles
    const int dhi = dlo + 1;

    // ---- B-frags for layer 2 (all waves): W2[k=kh*32+g*8+e][n=cb*16+r] ----
    bf16x8 bfr[2][4];
#pragma unroll
    for (int kh = 0; kh < 2; ++kh)
#pragma unroll
        for (int cb = 0; cb < 4; ++cb) {
            const float* src = W2 + (kh * 32 + g * 8) * DD + cb * 16 + r;
            float t[8];
#pragma unroll
            for (int e = 0; e < 8; ++e) t[e] = src[e * DD];
            union { bf16x8 v8; unsigned u4[4]; } cvt;
            cvt.u4[0] = pk2bf(t[0], t[1]); cvt.u4[1] = pk2bf(t[2], t[3]);
            cvt.u4[2] = pk2bf(t[4], t[5]); cvt.u4[3] = pk2bf(t[6], t[7]);
            bfr[kh][cb] = cvt.v8;
        }
    float b2f[4], w3f[4];
#pragma unroll
    for (int cb = 0; cb < 4; ++cb) {
        b2f[cb] = b2[cb * 16 + r];
        w3f[cb] = W3[cb * 16 + r];
    }
    const float b3s = b3[0];

    float* __restrict__ ob = out + b * (MM * MM);

    // ---- prologue: compute u/v tiles into LDS ----
    // off-diag: wave0 -> tiles[0]=u(ib), wave1 -> tiles[1]=v(jb).
    // packed:   waves 0..3 -> tiles[w] = {u(dlo), v(dlo), u(dhi), v(dhi)}.
    if (wave < (packed ? 4 : 2)) {
        const int uv = wave & 1;
        const int tb = packed ? (dlo + (wave >> 1)) : (uv ? jb : ib);

        // W1 frags: W1[uv*64 + kh*32 + g*8 + e][cb*16 + r]
        bf16x8 w1f[2][4];
#pragma unroll
        for (int kh = 0; kh < 2; ++kh)
#pragma unroll
            for (int cb = 0; cb < 4; ++cb) {
                const float* src = W1 + (uv * DD + kh * 32 + g * 8) * DD + cb * 16 + r;
                float t[8];
#pragma unroll
                for (int e = 0; e < 8; ++e) t[e] = src[e * DD];
                union { bf16x8 v8; unsigned u4[4]; } cvt;
                cvt.u4[0] = pk2bf(t[0], t[1]); cvt.u4[1] = pk2bf(t[2], t[3]);
                cvt.u4[2] = pk2bf(t[4], t[5]); cvt.u4[3] = pk2bf(t[6], t[7]);
                w1f[kh][cb] = cvt.v8;
            }
        float b1f[4] = {0.0f, 0.0f, 0.0f, 0.0f};
        if (!uv) {
#pragma unroll
            for (int cb = 0; cb < 4; ++cb) b1f[cb] = b1[cb * 16 + r];
        }

        // token gather: this lane's A-row token = tb*16 + r
        const int tok = b * MM + tb * 16 + r;
        int p = positions[tok];
        p = p < 0 ? 0 : (p > PP - 1 ? PP - 1 : p);
        int a = amino[tok];
        a = a < 0 ? 0 : (a > AN - 1 ? AN - 1 : a);

        bf16x8 ef[2];
#pragma unroll
        for (int kh = 0; kh < 2; ++kh) {
            const int koff = kh * 32 + g * 8;
            const f32x4 p0 = *(const f32x4*)(pos_table + p * DD + koff);
            const f32x4 p1 = *(const f32x4*)(pos_table + p * DD + koff + 4);
            const f32x4 a0 = *(const f32x4*)(aa_table + a * DD + koff);
            const f32x4 a1 = *(const f32x4*)(aa_table + a * DD + koff + 4);
            const f32x4 e0 = p0 + a0;           // v_pk_add_f32 x2
            const f32x4 e1 = p1 + a1;
            union { bf16x8 v8; unsigned u4[4]; } cvt;
            cvt.u4[0] = pk2bf(e0[0], e0[1]);
            cvt.u4[1] = pk2bf(e0[2], e0[3]);
            cvt.u4[2] = pk2bf(e1[0], e1[1]);
            cvt.u4[3] = pk2bf(e1[2], e1[3]);
            ef[kh] = cvt.v8;
        }

        float (* __restrict__ dst)[UVP] = tiles[wave];
#pragma unroll
        for (int cb = 0; cb < 4; ++cb) {
            f32x4 z = {0.0f, 0.0f, 0.0f, 0.0f};
            z = __builtin_amdgcn_mfma_f32_16x16x32_bf16(ef[0], w1f[0][cb], z, 0, 0, 0);
            z = __builtin_amdgcn_mfma_f32_16x16x32_bf16(ef[1], w1f[1][cb], z, 0, 0, 0);
            // C/D: row = g*4+reg (token-in-tile), col = cb*16+r (feature)
#pragma unroll
            for (int reg = 0; reg < 4; ++reg)
                dst[g * 4 + reg][cb * 16 + r] = z[reg] + b1f[cb];
        }
    }

    // diagonal zeros: packed WGs own tokens dlo*16..+31
    if (packed && threadIdx.x < 32) {
        const int m = dlo * 16 + threadIdx.x;
        ob[m * (MM + 1)] = 0.0f;
    }

    __syncthreads();

#pragma unroll
    for (int tt = 0; tt < 2; ++tt) {
        const int ss = tt * 8 + wave;            // column-slot 0..15

        // per-lane LDS row selection for the A-build
        const float* up;                         // u-row (this lane's i)
        const float* vp;                         // v-row (this lane's j)
        int s = ss;
        if (packed) {
            s = ss ? ss : 8;                     // slot 0 duplicates slot 8
            const bool lo = r < s;
            up = lo ? &tiles[0][r][0]     : &tiles[2][r - s][0];
            vp = lo ? &tiles[1][s][0]     : &tiles[3][16 - s][0];
        } else {
            up = &tiles[0][r][0];
            vp = &tiles[1][ss][0];
        }

        // ---- layer 1: A frags from LDS; pk adds + paired gelu ----
        bf16x8 afr[2];
#pragma unroll
        for (int kh = 0; kh < 2; ++kh) {
            const int koff = kh * 32 + g * 8;
            const f32x4 u0 = *(const f32x4*)(up + koff);
            const f32x4 u1 = *(const f32x4*)(up + koff + 4);
            const f32x4 v0 = *(const f32x4*)(vp + koff);
            const f32x4 v1 = *(const f32x4*)(vp + koff + 4);
            const f32x4 x0 = u0 + v0;            // v_pk_add_f32 x2
            const f32x4 x1 = u1 + v1;
            const f32x2 g0 = gelu2(__builtin_shufflevector(x0, x0, 0, 1));
            const f32x2 g1 = gelu2(__builtin_shufflevector(x0, x0, 2, 3));
            const f32x2 g2 = gelu2(__builtin_shufflevector(x1, x1, 0, 1));
            const f32x2 g3 = gelu2(__builtin_shufflevector(x1, x1, 2, 3));
            union { bf16x8 v8; unsigned u4[4]; } cvt;
            cvt.u4[0] = pk2bf(g0[0], g0[1]);
            cvt.u4[1] = pk2bf(g1[0], g1[1]);
            cvt.u4[2] = pk2bf(g2[0], g2[1]);
            cvt.u4[3] = pk2bf(g3[0], g3[1]);
            afr[kh] = cvt.v8;
        }

        // ---- layer 2: 8 MFMAs ----
        f32x4 acc[4];
#pragma unroll
        for (int cb = 0; cb < 4; ++cb) {
            f32x4 z = {0.0f, 0.0f, 0.0f, 0.0f};
            z = __builtin_amdgcn_mfma_f32_16x16x32_bf16(afr[0], bfr[0][cb], z, 0, 0, 0);
            acc[cb] = __builtin_amdgcn_mfma_f32_16x16x32_bf16(afr[1], bfr[1][cb], z, 0, 0, 0);
        }

        // ---- layer 3: paired gelu + pk W3 fma, DPP row-sum ----
        f32x2 a01 = {0.0f, 0.0f}, a23 = {0.0f, 0.0f};
#pragma unroll
        for (int cb = 0; cb < 4; ++cb) {
            const f32x2 bb = {b2f[cb], b2f[cb]};
            const f32x2 ww = {w3f[cb], w3f[cb]};
            const f32x2 lo = (f32x2){acc[cb][0], acc[cb][1]} + bb;   // pk_add
            const f32x2 hi = (f32x2){acc[cb][2], acc[cb][3]} + bb;
            a01 = __builtin_elementwise_fma(gelu2(lo), ww, a01);     // pk_fma
            a23 = __builtin_elementwise_fma(gelu2(hi), ww, a23);
        }
        const float s0 = row_sum16(a01[0]) + b3s;
        const float s1 = row_sum16(a01[1]) + b3s;
        const float s2 = row_sum16(a23[0]) + b3s;
        const float s3 = row_sum16(a23[1]) + b3s;

        // ---- store: lane (g, r<4) owns C row p = g*4+r of this column ----
        if (r < 4) {
            const int p = g * 4 + r;
            const float sc = (r == 0) ? s0 : (r == 1) ? s1 : (r == 2) ? s2 : s3;
            int ig, jg;
            if (packed) {
                const bool lo = p < s;
                ig = lo ? dlo * 16 + p : dhi * 16 + (p - s);
                jg = lo ? dlo * 16 + s : dhi * 16 + (16 - s);
            } else {
                ig = ib * 16 + p;
                jg = jb * 16 + ss;
            }
            ob[ig * MM + jg] = sc;               // column (scattered)
            ob[jg * MM + ig] = sc;               // mirror row (coalesced)
        }
    }
}

extern "C" void kernel_launch(void* const* d_in, const int* in_sizes, int n_in,
                              void* d_out, int out_size, void* d_ws, size_t ws_size,
                              hipStream_t stream) {
    const int*   positions = (const int*)  d_in[0];
    const int*   amino     = (const int*)  d_in[1];
    const float* pos_table = (const float*)d_in[2];
    const float* aa_table  = (const float*)d_in[3];
    const float* W1        = (const float*)d_in[4];
    const float* b1        = (const float*)d_in[5];
    const float* W2        = (const float*)d_in[6];
    const float* b2        = (const float*)d_in[7];
    const float* W3        = (const float*)d_in[8];
    const float* b3        = (const float*)d_in[9];
    float* out = (float*)d_out;

    // Single fused launch: (6 off-diag + 2 packed-diag) x 128 batches,
    // 512 threads (8 waves x 2 column-slots).
    k_fused<<<dim3(8, 128), 512, 0, stream>>>(positions, amino, pos_table,
                                              aa_table, W1, b1, W2, b2, W3, b3,
                                              out);
}

// Round 14
// 23.657 us; speedup vs baseline: 1.1858x; 1.1858x over previous
//
#include <hip/hip_runtime.h>
#include <hip/hip_bf16.h>
#include <cmath>

// Problem constants
#define BB 128
#define MM 64
#define DD 64
#define PP 1024
#define AN 21
#define UVP 68                          // padded u/v LDS row stride

typedef __attribute__((ext_vector_type(8))) short bf16x8;   // 8 bf16 = 4 VGPRs
typedef __attribute__((ext_vector_type(4))) float f32x4;    // MFMA C/D + pk math
typedef __attribute__((ext_vector_type(2))) float f32x2;    // v_pk_*_f32 pairs

// paired tanh-approx GELU: 6 packed-f32 VALU (v_pk_mul/add/fma) + 4 trans
// per TWO gelus. Same approximation as the scalar 7-slot version,
// re-associated: x + c x^3 == x*(1 + c x^2).
__device__ __forceinline__ f32x2 gelu2(f32x2 x) {
    const f32x2 x2 = x * x;                                        // pk_mul
    const f32x2 q  = __builtin_elementwise_fma(
        x2, (f32x2){0.044715f, 0.044715f}, (f32x2){1.0f, 1.0f});   // pk_fma
    const f32x2 p  = x * q;                                        // pk_mul
    const f32x2 zm = p * (f32x2){2.3022150322f, 2.3022150322f};    // pk_mul
    f32x2 z;
    z[0] = __builtin_amdgcn_exp2f(zm[0]);                          // trans
    z[1] = __builtin_amdgcn_exp2f(zm[1]);                          // trans
    const f32x2 zp = z + (f32x2){1.0f, 1.0f};                      // pk_add
    f32x2 r;
    r[0] = __builtin_amdgcn_rcpf(zp[0]);                           // trans
    r[1] = __builtin_amdgcn_rcpf(zp[1]);                           // trans
    return __builtin_elementwise_fma(-x, r, x);                    // pk_fma
}

// pack 2 floats -> 1 u32 of 2 bf16 (emits v_cvt_pk_bf16_f32)
__device__ __forceinline__ unsigned pk2bf(float lo, float hi) {
    __hip_bfloat162 t = __float22bfloat162_rn(make_float2(lo, hi));
    unsigned u; __builtin_memcpy(&u, &t, 4);
    return u;
}

// butterfly sum over each 16-lane row via DPP (xor 1,2,4,8)
__device__ __forceinline__ float row_sum16(float x) {
    int t;
    t = __builtin_amdgcn_update_dpp(0, __float_as_int(x), 0xB1, 0xF, 0xF, true); // xor1
    x += __int_as_float(t);
    t = __builtin_amdgcn_update_dpp(0, __float_as_int(x), 0x4E, 0xF, 0xF, true); // xor2
    x += __int_as_float(t);
    t = __builtin_amdgcn_update_dpp(0, __float_as_int(x), 0x141, 0xF, 0xF, true); // xor4
    x += __int_as_float(t);
    t = __builtin_amdgcn_update_dpp(0, __float_as_int(x), 0x140, 0xF, 0xF, true); // xor8
    x += __int_as_float(t);
    return x;
}

// ---------------------------------------------------------------------------
// FUSED kernel, diagonal-packed (round-11 structure) + packed-f32 VALU.
// REVERTED to the round-12 configuration: 256-thread WGs, 4 column-slots
// per wave. Round 13's 512-thread variant regressed (+3.8us): prologue
// serialization (waves 4-7 idle at the barrier), halved amortization of the
// hoisted W2/W1 fragment setup (2 slots/wave, 8 waves paying setup), and
// 8-wave barrier cost outweighed the occupancy gain. 4 slots/wave is the
// measured amortization/occupancy optimum.
// Grid (8, 128) = 1024 WGs (4 WG/CU).
// blk 0..5: strictly-upper 16x16 blocks (ib<jb).
// blk 6..7: two diagonal triangles packed per WG via column-slot scheme
//   (slot s: lanes r<s -> pair (r,s) of d0; r>=s -> (r-s, 16-s) of d1;
//    slot 0 duplicates slot 8 -- benign identical stores).
// Prologue: u/v tiles MFMA'd into LDS (one wave per tile); W2/W1 fragments
// from stride-64 scalar loads (L1-hot); all f32 elementwise math in
// f32x2/f32x4 ext-vectors -> v_pk_*_f32 dual-issue ops.
// ---------------------------------------------------------------------------
__global__ __launch_bounds__(256) void k_fused(
    const int* __restrict__ positions, const int* __restrict__ amino,
    const float* __restrict__ pos_table, const float* __restrict__ aa_table,
    const float* __restrict__ W1, const float* __restrict__ b1,
    const float* __restrict__ W2, const float* __restrict__ b2,
    const float* __restrict__ W3, const float* __restrict__ b3,
    float* __restrict__ out)
{
    __shared__ __align__(16) float tiles[4][16][UVP];
    const int lane = threadIdx.x & 63;
    const int wave = threadIdx.x >> 6;
    const int r = lane & 15;        // A row (build) / C col (output feature)
    const int g = lane >> 4;        // k-group

    const int blk = blockIdx.x;     // 0..7
    const int b   = blockIdx.y;     // 0..127
    const bool packed = (blk >= 6);
    // off-diag (ib, jb) tables, 3 bits each: blocks {01,02,03,12,13,23}
    const int ib = (0x11200u >> (3 * blk)) & 7;
    const int jb = (0x1B4D1u >> (3 * blk)) & 7;
    const int dlo = packed ? 2 * (blk - 6) : 0;     // packed triangle tiles
    const int dhi = dlo + 1;

    // ---- B-frags for layer 2 (all waves): W2[k=kh*32+g*8+e][n=cb*16+r] ----
    bf16x8 bfr[2][4];
#pragma unroll
    for (int kh = 0; kh < 2; ++kh)
#pragma unroll
        for (int cb = 0; cb < 4; ++cb) {
            const float* src = W2 + (kh * 32 + g * 8) * DD + cb * 16 + r;
            float t[8];
#pragma unroll
            for (int e = 0; e < 8; ++e) t[e] = src[e * DD];
            union { bf16x8 v8; unsigned u4[4]; } cvt;
            cvt.u4[0] = pk2bf(t[0], t[1]); cvt.u4[1] = pk2bf(t[2], t[3]);
            cvt.u4[2] = pk2bf(t[4], t[5]); cvt.u4[3] = pk2bf(t[6], t[7]);
            bfr[kh][cb] = cvt.v8;
        }
    float b2f[4], w3f[4];
#pragma unroll
    for (int cb = 0; cb < 4; ++cb) {
        b2f[cb] = b2[cb * 16 + r];
        w3f[cb] = W3[cb * 16 + r];
    }
    const float b3s = b3[0];

    float* __restrict__ ob = out + b * (MM * MM);

    // ---- prologue: compute u/v tiles into LDS ----
    // off-diag: wave0 -> tiles[0]=u(ib), wave1 -> tiles[1]=v(jb).
    // packed:   wave w -> tiles[w] = {u(dlo), v(dlo), u(dhi), v(dhi)}.
    if (packed || wave < 2) {
        const int uv = wave & 1;
        const int tb = packed ? (dlo + (wave >> 1)) : (uv ? jb : ib);

        // W1 frags: W1[uv*64 + kh*32 + g*8 + e][cb*16 + r]
        bf16x8 w1f[2][4];
#pragma unroll
        for (int kh = 0; kh < 2; ++kh)
#pragma unroll
            for (int cb = 0; cb < 4; ++cb) {
                const float* src = W1 + (uv * DD + kh * 32 + g * 8) * DD + cb * 16 + r;
                float t[8];
#pragma unroll
                for (int e = 0; e < 8; ++e) t[e] = src[e * DD];
                union { bf16x8 v8; unsigned u4[4]; } cvt;
                cvt.u4[0] = pk2bf(t[0], t[1]); cvt.u4[1] = pk2bf(t[2], t[3]);
                cvt.u4[2] = pk2bf(t[4], t[5]); cvt.u4[3] = pk2bf(t[6], t[7]);
                w1f[kh][cb] = cvt.v8;
            }
        float b1f[4] = {0.0f, 0.0f, 0.0f, 0.0f};
        if (!uv) {
#pragma unroll
            for (int cb = 0; cb < 4; ++cb) b1f[cb] = b1[cb * 16 + r];
        }

        // token gather: this lane's A-row token = tb*16 + r
        const int tok = b * MM + tb * 16 + r;
        int p = positions[tok];
        p = p < 0 ? 0 : (p > PP - 1 ? PP - 1 : p);
        int a = amino[tok];
        a = a < 0 ? 0 : (a > AN - 1 ? AN - 1 : a);

        bf16x8 ef[2];
#pragma unroll
        for (int kh = 0; kh < 2; ++kh) {
            const int koff = kh * 32 + g * 8;
            const f32x4 p0 = *(const f32x4*)(pos_table + p * DD + koff);
            const f32x4 p1 = *(const f32x4*)(pos_table + p * DD + koff + 4);
            const f32x4 a0 = *(const f32x4*)(aa_table + a * DD + koff);
            const f32x4 a1 = *(const f32x4*)(aa_table + a * DD + koff + 4);
            const f32x4 e0 = p0 + a0;           // v_pk_add_f32 x2
            const f32x4 e1 = p1 + a1;
            union { bf16x8 v8; unsigned u4[4]; } cvt;
            cvt.u4[0] = pk2bf(e0[0], e0[1]);
            cvt.u4[1] = pk2bf(e0[2], e0[3]);
            cvt.u4[2] = pk2bf(e1[0], e1[1]);
            cvt.u4[3] = pk2bf(e1[2], e1[3]);
            ef[kh] = cvt.v8;
        }

        float (* __restrict__ dst)[UVP] = tiles[wave];
#pragma unroll
        for (int cb = 0; cb < 4; ++cb) {
            f32x4 z = {0.0f, 0.0f, 0.0f, 0.0f};
            z = __builtin_amdgcn_mfma_f32_16x16x32_bf16(ef[0], w1f[0][cb], z, 0, 0, 0);
            z = __builtin_amdgcn_mfma_f32_16x16x32_bf16(ef[1], w1f[1][cb], z, 0, 0, 0);
            // C/D: row = g*4+reg (token-in-tile), col = cb*16+r (feature)
#pragma unroll
            for (int reg = 0; reg < 4; ++reg)
                dst[g * 4 + reg][cb * 16 + r] = z[reg] + b1f[cb];
        }
    }

    // diagonal zeros: packed WGs own tokens dlo*16..+31
    if (packed && threadIdx.x < 32) {
        const int m = dlo * 16 + threadIdx.x;
        ob[m * (MM + 1)] = 0.0f;
    }

    __syncthreads();

#pragma unroll
    for (int tt = 0; tt < 4; ++tt) {
        const int ss = tt * 4 + wave;            // column-slot 0..15

        // per-lane LDS row selection for the A-build
        const float* up;                         // u-row (this lane's i)
        const float* vp;                         // v-row (this lane's j)
        int s = ss;
        if (packed) {
            s = ss ? ss : 8;                     // slot 0 duplicates slot 8
            const bool lo = r < s;
            up = lo ? &tiles[0][r][0]     : &tiles[2][r - s][0];
            vp = lo ? &tiles[1][s][0]     : &tiles[3][16 - s][0];
        } else {
            up = &tiles[0][r][0];
            vp = &tiles[1][ss][0];
        }

        // ---- layer 1: A frags from LDS; pk adds + paired gelu ----
        bf16x8 afr[2];
#pragma unroll
        for (int kh = 0; kh < 2; ++kh) {
            const int koff = kh * 32 + g * 8;
            const f32x4 u0 = *(const f32x4*)(up + koff);
            const f32x4 u1 = *(const f32x4*)(up + koff + 4);
            const f32x4 v0 = *(const f32x4*)(vp + koff);
            const f32x4 v1 = *(const f32x4*)(vp + koff + 4);
            const f32x4 x0 = u0 + v0;            // v_pk_add_f32 x2
            const f32x4 x1 = u1 + v1;
            const f32x2 g0 = gelu2(__builtin_shufflevector(x0, x0, 0, 1));
            const f32x2 g1 = gelu2(__builtin_shufflevector(x0, x0, 2, 3));
            const f32x2 g2 = gelu2(__builtin_shufflevector(x1, x1, 0, 1));
            const f32x2 g3 = gelu2(__builtin_shufflevector(x1, x1, 2, 3));
            union { bf16x8 v8; unsigned u4[4]; } cvt;
            cvt.u4[0] = pk2bf(g0[0], g0[1]);
            cvt.u4[1] = pk2bf(g1[0], g1[1]);
            cvt.u4[2] = pk2bf(g2[0], g2[1]);
            cvt.u4[3] = pk2bf(g3[0], g3[1]);
            afr[kh] = cvt.v8;
        }

        // ---- layer 2: 8 MFMAs ----
        f32x4 acc[4];
#pragma unroll
        for (int cb = 0; cb < 4; ++cb) {
            f32x4 z = {0.0f, 0.0f, 0.0f, 0.0f};
            z = __builtin_amdgcn_mfma_f32_16x16x32_bf16(afr[0], bfr[0][cb], z, 0, 0, 0);
            acc[cb] = __builtin_amdgcn_mfma_f32_16x16x32_bf16(afr[1], bfr[1][cb], z, 0, 0, 0);
        }

        // ---- layer 3: paired gelu + pk W3 fma, DPP row-sum ----
        f32x2 a01 = {0.0f, 0.0f}, a23 = {0.0f, 0.0f};
#pragma unroll
        for (int cb = 0; cb < 4; ++cb) {
            const f32x2 bb = {b2f[cb], b2f[cb]};
            const f32x2 ww = {w3f[cb], w3f[cb]};
            const f32x2 lo = (f32x2){acc[cb][0], acc[cb][1]} + bb;   // pk_add
            const f32x2 hi = (f32x2){acc[cb][2], acc[cb][3]} + bb;
            a01 = __builtin_elementwise_fma(gelu2(lo), ww, a01);     // pk_fma
            a23 = __builtin_elementwise_fma(gelu2(hi), ww, a23);
        }
        const float s0 = row_sum16(a01[0]) + b3s;
        const float s1 = row_sum16(a01[1]) + b3s;
        const float s2 = row_sum16(a23[0]) + b3s;
        const float s3 = row_sum16(a23[1]) + b3s;

        // ---- store: lane (g, r<4) owns C row p = g*4+r of this column ----
        if (r < 4) {
            const int p = g * 4 + r;
            const float sc = (r == 0) ? s0 : (r == 1) ? s1 : (r == 2) ? s2 : s3;
            int ig, jg;
            if (packed) {
                const bool lo = p < s;
                ig = lo ? dlo * 16 + p : dhi * 16 + (p - s);
                jg = lo ? dlo * 16 + s : dhi * 16 + (16 - s);
            } else {
                ig = ib * 16 + p;
                jg = jb * 16 + ss;
            }
            ob[ig * MM + jg] = sc;               // column (scattered)
            ob[jg * MM + ig] = sc;               // mirror row (coalesced)
        }
    }
}

extern "C" void kernel_launch(void* const* d_in, const int* in_sizes, int n_in,
                              void* d_out, int out_size, void* d_ws, size_t ws_size,
                              hipStream_t stream) {
    const int*   positions = (const int*)  d_in[0];
    const int*   amino     = (const int*)  d_in[1];
    const float* pos_table = (const float*)d_in[2];
    const float* aa_table  = (const float*)d_in[3];
    const float* W1        = (const float*)d_in[4];
    const float* b1        = (const float*)d_in[5];
    const float* W2        = (const float*)d_in[6];
    const float* b2        = (const float*)d_in[7];
    const float* W3        = (const float*)d_in[8];
    const float* b3        = (const float*)d_in[9];
    float* out = (float*)d_out;

    // Single fused launch: (6 off-diag + 2 packed-diag) x 128 batches.
    k_fused<<<dim3(8, 128), 256, 0, stream>>>(positions, amino, pos_table,
                                              aa_table, W1, b1, W2, b2, W3, b3,
                                              out);
}